// Round 4
// baseline (201.177 us; speedup 1.0000x reference)
//
#include <hip/hip_runtime.h>

#define B_TOT 65536
#define T_STEPS 10
#define D_IN 16
#define H 64
#define G4H 256
#define D_MLP 30
#define D_OUT 4
#define BTILE 32
#define PSTR 72     // h-plane row stride (shorts): 144B rows -> ds_read_b128 ALIGNED; 36dw -> 2-way only
#define DSTR 32     // d buffer row stride (shorts): 64B rows -> aligned + contiguous ad reads
#define LOG2E 1.44269504088896340736f
#define TWO_LOG2E 2.88539008177792681472f

typedef short short8 __attribute__((ext_vector_type(8)));
typedef float float4_t __attribute__((ext_vector_type(4)));
typedef __bf16 bf16x8_t __attribute__((ext_vector_type(8)));

static __device__ __forceinline__ short f2bf(float f) {  // round-half-up (activations)
    unsigned u = __builtin_bit_cast(unsigned, f);
    return (short)(unsigned short)((u + 0x8000u) >> 16);
}
static __device__ __forceinline__ short f2bf_rne(float f) {  // weights
    unsigned u = __builtin_bit_cast(unsigned, f);
    unsigned r = (u + 0x7FFFu + ((u >> 16) & 1u)) >> 16;
    return (short)(unsigned short)r;
}
static __device__ __forceinline__ float bf2f(short s) {
    unsigned u = ((unsigned)(unsigned short)s) << 16;
    return __builtin_bit_cast(float, u);
}
static __device__ __forceinline__ float4_t mfma16(short8 a, short8 b, float4_t c) {
    return __builtin_amdgcn_mfma_f32_16x16x32_bf16(
        __builtin_bit_cast(bf16x8_t, a), __builtin_bit_cast(bf16x8_t, b), c, 0, 0, 0);
}
// z pre-scaled by log2e in the weights: sigmoid(z) = 1/(1+2^-z')
static __device__ __forceinline__ float sigm2(float z) {
    return __builtin_amdgcn_rcpf(1.0f + __builtin_amdgcn_exp2f(-z));
}
// pack two f32 -> one dword of 2 bf16 (round-half-up, same bits as f2bf pairwise)
static __device__ __forceinline__ unsigned pk2bf(float lo, float hi) {
    const unsigned ulo = __builtin_bit_cast(unsigned, lo) + 0x8000u;
    const unsigned uhi = __builtin_bit_cast(unsigned, hi) + 0x8000u;
    return (ulo >> 16) | (uhi & 0xFFFF0000u);
}

// ---- workspace layout (bytes) ----
#define WS_WU1 0        // 48 frags x 1KB = 49152
#define WS_WU2 49152    // 48 frags = 49152
#define WS_WD  98304    // 4 frags = 4096
#define WS_BZ1 102400   // 256 f32
#define WS_B2P 103424   // 256 f32
#define WS_BDP 104448   // 32 f32

// Weights pre-swizzled to MFMA B-frag order (frag f, lane l, elem e -> B[k=(l>>4)*8+e][n=l&15])
// and pre-scaled: i/f/o gates by log2e, L1 g-gate by 2*log2e, L2 g-gate (relu) raw.
// wu1: A1=[h1(0:64)|x-reg], kt0=U1[0:32], kt1=U1[32:64], kt2=[W1(16);zeros(16)]
// wu2: A2=[d(0:32)|h2(0:64)], kt0=[W2(30);0;0], kt1=U2[0:32], kt2=U2[32:64]
// wd : d = h1 @ Wd (cols padded 30->32), unscaled
__global__ void precompute(const float* __restrict__ W1, const float* __restrict__ U1,
                           const float* __restrict__ b1, const float* __restrict__ Wd,
                           const float* __restrict__ bd, const float* __restrict__ W2,
                           const float* __restrict__ U2, const float* __restrict__ b2,
                           short* __restrict__ wu1_sw, short* __restrict__ wu2_sw,
                           short* __restrict__ wd_sw, float* __restrict__ bz1,
                           float* __restrict__ b2p, float* __restrict__ bdp) {
    const int lane = threadIdx.x;  // 64
    const int b = blockIdx.x;      // 101
    if (b < 48) {
        const int f = b, jt = f / 12, g = (f / 3) & 3, kt = f % 3;
        const int col = g * 64 + jt * 16 + (lane & 15);
        const float sc = (g == 2) ? TWO_LOG2E : LOG2E;
        for (int e = 0; e < 8; ++e) {
            const int sub = (lane >> 4) * 8 + e;  // 0..31
            float v;
            if (kt == 0)      v = U1[sub * G4H + col];
            else if (kt == 1) v = U1[(sub + 32) * G4H + col];
            else              v = (sub < 16) ? W1[sub * G4H + col] : 0.0f;
            wu1_sw[(f * 64 + lane) * 8 + e] = f2bf_rne(v * sc);
        }
    } else if (b < 96) {
        const int f = b - 48, jt = f / 12, g = (f / 3) & 3, kt = f % 3;
        const int col = g * 64 + jt * 16 + (lane & 15);
        const float sc = (g == 2) ? 1.0f : LOG2E;  // relu gate stays raw
        for (int e = 0; e < 8; ++e) {
            const int sub = (lane >> 4) * 8 + e;
            float v;
            if (kt == 0)      v = (sub < D_MLP) ? W2[sub * G4H + col] : 0.0f;
            else if (kt == 1) v = U2[sub * G4H + col];
            else              v = U2[(sub + 32) * G4H + col];
            wu2_sw[(f * 64 + lane) * 8 + e] = f2bf_rne(v * sc);
        }
    } else if (b < 100) {
        const int fd = b - 96, nt = fd >> 1, kt = fd & 1;
        const int col = nt * 16 + (lane & 15);
        for (int e = 0; e < 8; ++e) {
            const int k = kt * 32 + (lane >> 4) * 8 + e;  // h1 dim 0..63
            const float v = (col < D_MLP) ? Wd[k * D_MLP + col] : 0.0f;
            wd_sw[(fd * 64 + lane) * 8 + e] = f2bf_rne(v);
        }
    } else {
        for (int i = 0; i < 4; ++i) {
            const int c = i * 64 + lane;
            const int g = c >> 6;
            bz1[c] = b1[c] * ((g == 2) ? TWO_LOG2E : LOG2E);
            b2p[c] = b2[c] * ((g == 2) ? 1.0f : LOG2E);
        }
        if (lane < 32) bdp[lane] = (lane < D_MLP) ? bd[lane] : 0.0f;
    }
}

// ---------------- fully fused: LSTM1 -> Dense(D in LDS) -> LSTM2 -> projection ----------------
// Register strategy (r4): target the 64-VGPR tier (m69: waves/SIMD halves at 64/128; VGPR=80
// lands in the 4-wave tier while LDS permits 5 blocks/CU). Diet: px lane-packed f32 prefetch
// (16->8 regs, lanes>=32 carry m=1; upper-lane A-frag garbage is nulled by zero weights in
// wz[g][2] k>=16), and wd frags reloaded per-t from L2 via an anti-LICM opaque pointer (-8).
// waves_per_eu(4,8): the allocator targets the MAX (r1 evidence) -> 64-reg budget.
// TRIPWIRE: if WRITE_SIZE >> 1MB, this spilled -> revert attribute, keep diet.
__global__ __launch_bounds__(256)
__attribute__((amdgpu_waves_per_eu(4, 8)))
void lstm_all(const float* __restrict__ x, const short* __restrict__ wu1_sw,
              const short* __restrict__ wu2_sw, const short* __restrict__ wd_sw,
              const float* __restrict__ bz1, const float* __restrict__ b2p,
              const float* __restrict__ bdp, const float* __restrict__ Wf,
              const float* __restrict__ bfin, float* __restrict__ out) {
    __shared__ __align__(16) short P[2][BTILE * PSTR];        // 9216 B h-plane (dbuf)
    __shared__ __align__(16) short D[T_STEPS][BTILE * DSTR];  // 20480 B dense buffer
    // total 29696 B -> 5 blocks/CU (if VGPR <= 64)

    const int tid = threadIdx.x, lane = tid & 63, wave = tid >> 6;
    const int q = lane >> 4, n = lane & 15;
    const int b0 = blockIdx.x * BTILE;

    // ---- phase-1 weights: wave owns gate-col slice [g*64 + wave*16, +16) ----
    short8 wz[4][3];
    float bzv[4];
#pragma unroll
    for (int g = 0; g < 4; ++g) {
#pragma unroll
        for (int kt = 0; kt < 3; ++kt)
            wz[g][kt] = ((const short8*)wu1_sw)[(wave * 12 + g * 3 + kt) * 64 + lane];
        bzv[g] = bz1[g * 64 + wave * 16 + n];
    }
    // d-projection: wave -> (row-tile mw, col-tile ntw); wd frags are re-loaded per-t (L2-hot)
    const int mw = wave >> 1, ntw = wave & 1;
    const float bdv = bdp[ntw * 16 + n];

    for (int i = tid; i < BTILE * PSTR; i += 256) P[0][i] = 0;

    float4_t cc[2];
    cc[0] = (float4_t){0, 0, 0, 0};
    cc[1] = (float4_t){0, 0, 0, 0};

    // x loads, lane-packed: EVERY lane loads its own 8 f32.
    // lane<32 -> m=0 rows (b0+n), lane>=32 -> m=1 rows (b0+16+n); k-half = (lane>>4)&1.
    const float* xlane = x + (size_t)(b0 + (lane >> 5) * 16 + n) * (T_STEPS * D_IN)
                           + ((lane >> 4) & 1) * 8;
    float4 px0 = *(const float4*)xlane;
    float4 px1 = *(const float4*)(xlane + 4);
    __syncthreads();  // P[0] zeros visible

    // ================= phase 1: LSTM1 (tanh) + Dense into D =================
    for (int t = 0; t < T_STEPS; ++t) {
        const short* cb = P[t & 1];
        short* nb = P[(t & 1) ^ 1];

        // wd frags: opaque pointer defeats LICM -> re-loaded each t, live range ends at d-proj.
        // The h-barrier below drains vmcnt, so they are guaranteed arrived before use.
        const short8* wp = (const short8*)wd_sw + (ntw * 2) * 64 + lane;
        asm volatile("" : "+v"(wp));
        const short8 wda = wp[0];
        const short8 wdb = wp[64];

        // build A-frags for x from lane-packed px: ax[0] = own data (lanes>=32 garbage -> *0),
        // ax[1] = cross-half swap (lanes>=32 garbage -> *0).
        uint4 axu;
        axu.x = pk2bf(px0.x, px0.y);
        axu.y = pk2bf(px0.z, px0.w);
        axu.z = pk2bf(px1.x, px1.y);
        axu.w = pk2bf(px1.z, px1.w);
        short8 axm[2];
        axm[0] = __builtin_bit_cast(short8, axu);
        uint4 axv;
        axv.x = __shfl_xor((int)axu.x, 32);
        axv.y = __shfl_xor((int)axu.y, 32);
        axv.z = __shfl_xor((int)axu.z, 32);
        axv.w = __shfl_xor((int)axu.w, 32);
        axm[1] = __builtin_bit_cast(short8, axv);

        const int tn = (t + 1 < T_STEPS) ? t + 1 : T_STEPS - 1;
        px0 = *(const float4*)(xlane + tn * D_IN);
        px1 = *(const float4*)(xlane + tn * D_IN + 4);

#pragma unroll
        for (int m = 0; m < 2; ++m) {
            const int arow = (16 * m + n) * PSTR + q * 8;
            const short8 ah0 = *(const short8*)&cb[arow];
            const short8 ah1 = *(const short8*)&cb[arow + 32];
            float4_t ac[4];
#pragma unroll
            for (int g = 0; g < 4; ++g) {
                float4_t c = (float4_t){bzv[g], bzv[g], bzv[g], bzv[g]};
                c = mfma16(ah0, wz[g][0], c);
                c = mfma16(ah1, wz[g][1], c);
                c = mfma16(axm[m], wz[g][2], c);
                ac[g] = c;
            }
            // merged-rcp activation: 5 exp2 + 2 rcp per cell.
            // cn = c/(1+F) + (Q-1)/((1+B)(Q+1)) = [c*u + (Q-1)*v] * rcp(u*v),
            //   u=(1+B)(Q+1), v=(1+F);  h = (P-1) * rcp((1+A)(P+1)), P=2^(2*log2e*cn).
#pragma unroll
            for (int jj = 0; jj < 4; ++jj) {
                const float Bv = __builtin_amdgcn_exp2f(-ac[0][jj]);  // 2^-zi'
                const float Fv = __builtin_amdgcn_exp2f(-ac[1][jj]);  // 2^-zf'
                const float Qv = __builtin_amdgcn_exp2f(ac[2][jj]);   // 2^{zg''}
                const float Av = __builtin_amdgcn_exp2f(-ac[3][jj]);  // 2^-zo'
                const float uu = (1.0f + Bv) * (Qv + 1.0f);
                const float vv = 1.0f + Fv;
                const float num = cc[m][jj] * uu + (Qv - 1.0f) * vv;
                const float cn = num * __builtin_amdgcn_rcpf(uu * vv);
                cc[m][jj] = cn;
                const float Pv = __builtin_amdgcn_exp2f(cn * TWO_LOG2E);
                const float ww = (1.0f + Av) * (Pv + 1.0f);
                const float hh = (Pv - 1.0f) * __builtin_amdgcn_rcpf(ww);
                nb[(16 * m + q * 4 + jj) * PSTR + wave * 16 + n] = f2bf(hh);
            }
        }
        __syncthreads();  // h1_t complete (also drains wd/px loads)

        // d_t = h1_t @ Wd + bd -> D[t]  (each wave: one 16x16 tile, k=64)
        {
            const int drow = (16 * mw + n) * PSTR + q * 8;
            const short8 dh0 = *(const short8*)&nb[drow];
            const short8 dh1 = *(const short8*)&nb[drow + 32];
            float4_t dd = (float4_t){bdv, bdv, bdv, bdv};
            dd = mfma16(dh0, wda, dd);
            dd = mfma16(dh1, wdb, dd);
            short* dt = &D[t][0];
#pragma unroll
            for (int jj = 0; jj < 4; ++jj)
                dt[(16 * mw + q * 4 + jj) * DSTR + ntw * 16 + n] = f2bf(dd[jj]);
        }
    }

    // ================= phase boundary =================
    __syncthreads();  // all d-reads of P done before re-zeroing
#pragma unroll
    for (int g = 0; g < 4; ++g) {
#pragma unroll
        for (int kt = 0; kt < 3; ++kt)
            wz[g][kt] = ((const short8*)wu2_sw)[(wave * 12 + g * 3 + kt) * 64 + lane];
        bzv[g] = b2p[g * 64 + wave * 16 + n];
    }
    cc[0] = (float4_t){0, 0, 0, 0};
    cc[1] = (float4_t){0, 0, 0, 0};
    for (int i = tid; i < BTILE * PSTR; i += 256) P[0][i] = 0;
    __syncthreads();

    // ================= phase 2: LSTM2 (relu) from D =================
    for (int t = 0; t < T_STEPS; ++t) {
        const short* cb = P[t & 1];
        short* nb = P[(t & 1) ^ 1];

#pragma unroll
        for (int m = 0; m < 2; ++m) {
            const int ar = 16 * m + n;
            const short8 ad  = *(const short8*)&D[t][ar * DSTR + q * 8];
            const short8 ah0 = *(const short8*)&cb[ar * PSTR + q * 8];
            const short8 ah1 = *(const short8*)&cb[ar * PSTR + 32 + q * 8];
            float4_t ac[4];
#pragma unroll
            for (int g = 0; g < 4; ++g) {
                float4_t c = (float4_t){bzv[g], bzv[g], bzv[g], bzv[g]};
                c = mfma16(ad, wz[g][0], c);
                c = mfma16(ah0, wz[g][1], c);
                c = mfma16(ah1, wz[g][2], c);
                ac[g] = c;
            }
#pragma unroll
            for (int jj = 0; jj < 4; ++jj) {
                const float iv = sigm2(ac[0][jj]);
                const float fv = sigm2(ac[1][jj]);
                const float gv = fmaxf(ac[2][jj], 0.0f);   // raw (unscaled) gate
                const float ov = sigm2(ac[3][jj]);
                const float cn = fv * cc[m][jj] + iv * gv;
                cc[m][jj] = cn;
                nb[(16 * m + q * 4 + jj) * PSTR + wave * 16 + n] = f2bf(ov * fmaxf(cn, 0.0f));
            }
        }
        __syncthreads();
    }

    // ---- out = h2_9 @ Wf + bf ; t=9 wrote nb = P[0] ----
    if (tid < 128) {
        const int r = tid >> 2, c = tid & 3;
        float s = bfin[c];
#pragma unroll
        for (int kb = 0; kb < 8; ++kb) {
            const short8 h8 = *(const short8*)&P[0][r * PSTR + kb * 8];
#pragma unroll
            for (int e = 0; e < 8; ++e)
                s += bf2f(h8[e]) * Wf[(kb * 8 + e) * D_OUT + c];
        }
        out[(size_t)(b0 + r) * D_OUT + c] = s;
    }
}

extern "C" void kernel_launch(void* const* d_in, const int* in_sizes, int n_in,
                              void* d_out, int out_size, void* d_ws, size_t ws_size,
                              hipStream_t stream) {
    const float* x  = (const float*)d_in[0];
    const float* W1 = (const float*)d_in[1];
    const float* U1 = (const float*)d_in[2];
    const float* b1 = (const float*)d_in[3];
    const float* Wd = (const float*)d_in[4];
    const float* bd = (const float*)d_in[5];
    const float* W2 = (const float*)d_in[6];
    const float* U2 = (const float*)d_in[7];
    const float* b2 = (const float*)d_in[8];
    const float* Wf = (const float*)d_in[9];
    const float* bf = (const float*)d_in[10];
    float* out = (float*)d_out;

    char* ws = (char*)d_ws;
    short* wu1_sw = (short*)(ws + WS_WU1);
    short* wu2_sw = (short*)(ws + WS_WU2);
    short* wd_sw  = (short*)(ws + WS_WD);
    float* bz1    = (float*)(ws + WS_BZ1);
    float* b2p    = (float*)(ws + WS_B2P);
    float* bdp    = (float*)(ws + WS_BDP);

    precompute<<<101, 64, 0, stream>>>(W1, U1, b1, Wd, bd, W2, U2, b2,
                                       wu1_sw, wu2_sw, wd_sw, bz1, b2p, bdp);
    lstm_all<<<B_TOT / BTILE, 256, 0, stream>>>(x, wu1_sw, wu2_sw, wd_sw,
                                                bz1, b2p, bdp, Wf, bf, out);
}

// Round 6
// 187.057 us; speedup vs baseline: 1.0755x; 1.0755x over previous
//
#include <hip/hip_runtime.h>

#define B_TOT 65536
#define T_STEPS 10
#define D_IN 16
#define H 64
#define G4H 256
#define D_MLP 30
#define D_OUT 4
#define BTILE 32
#define PSTR 72     // h-plane row stride (shorts): 144B rows -> ds_read_b128 ALIGNED; 36dw -> 2-way only
#define DSTR 32     // d buffer row stride (shorts): 64B rows -> aligned + contiguous ad reads
#define LOG2E 1.44269504088896340736f
#define TWO_LOG2E 2.88539008177792681472f

typedef short short8 __attribute__((ext_vector_type(8)));
typedef float float4_t __attribute__((ext_vector_type(4)));
typedef __bf16 bf16x8_t __attribute__((ext_vector_type(8)));

static __device__ __forceinline__ short f2bf(float f) {  // round-half-up (activations)
    unsigned u = __builtin_bit_cast(unsigned, f);
    return (short)(unsigned short)((u + 0x8000u) >> 16);
}
static __device__ __forceinline__ short f2bf_rne(float f) {  // weights
    unsigned u = __builtin_bit_cast(unsigned, f);
    unsigned r = (u + 0x7FFFu + ((u >> 16) & 1u)) >> 16;
    return (short)(unsigned short)r;
}
static __device__ __forceinline__ float bf2f(short s) {
    unsigned u = ((unsigned)(unsigned short)s) << 16;
    return __builtin_bit_cast(float, u);
}
static __device__ __forceinline__ float4_t mfma16(short8 a, short8 b, float4_t c) {
    return __builtin_amdgcn_mfma_f32_16x16x32_bf16(
        __builtin_bit_cast(bf16x8_t, a), __builtin_bit_cast(bf16x8_t, b), c, 0, 0, 0);
}
// z pre-scaled by log2e in the weights: sigmoid(z) = 1/(1+2^-z')
static __device__ __forceinline__ float sigm2(float z) {
    return __builtin_amdgcn_rcpf(1.0f + __builtin_amdgcn_exp2f(-z));
}
// pack two f32 -> one dword of 2 bf16 (round-half-up, same bits as f2bf pairwise)
static __device__ __forceinline__ unsigned pk2bf(float lo, float hi) {
    const unsigned ulo = __builtin_bit_cast(unsigned, lo) + 0x8000u;
    const unsigned uhi = __builtin_bit_cast(unsigned, hi) + 0x8000u;
    return (ulo >> 16) | (uhi & 0xFFFF0000u);
}

// ---- workspace layout (bytes) ----
#define WS_WU1 0        // 48 frags x 1KB = 49152
#define WS_WU2 49152    // 48 frags = 49152
#define WS_WD  98304    // 4 frags = 4096
#define WS_BDP 102400   // 32 f32

// Weights pre-swizzled to MFMA B-frag order (frag f, lane l, elem e -> B[k=(l>>4)*8+e][n=l&15])
// and pre-scaled: i/f/o gates by log2e, L1 g-gate by 2*log2e, L2 g-gate (relu) raw.
// BIAS FOLDING (r5): b1 lives in wu1 kt2 row k=16 (activated by a 1.0 in the ax frag);
// b2 lives in wu2 kt0 row k=30 (activated by d[...,30]==1.0 via bdp[30]=1.0).
// wu1: A1=[h1(0:64)|x(16)|1|0...], kt0=U1[0:32], kt1=U1[32:64], kt2=[W1(16);b1;zeros(15)]
// wu2: A2=[d(0:30)|1|0|h2(0:64)], kt0=[W2(30);b2;0], kt1=U2[0:32], kt2=U2[32:64]
// wd : d = h1 @ Wd (cols padded 30->32, col30 forced to 1.0 via bdp), unscaled
__global__ void precompute(const float* __restrict__ W1, const float* __restrict__ U1,
                           const float* __restrict__ b1, const float* __restrict__ Wd,
                           const float* __restrict__ bd, const float* __restrict__ W2,
                           const float* __restrict__ U2, const float* __restrict__ b2,
                           short* __restrict__ wu1_sw, short* __restrict__ wu2_sw,
                           short* __restrict__ wd_sw, float* __restrict__ bdp) {
    const int lane = threadIdx.x;  // 64
    const int b = blockIdx.x;      // 101
    if (b < 48) {
        const int f = b, jt = f / 12, g = (f / 3) & 3, kt = f % 3;
        const int col = g * 64 + jt * 16 + (lane & 15);
        const float sc = (g == 2) ? TWO_LOG2E : LOG2E;
        for (int e = 0; e < 8; ++e) {
            const int sub = (lane >> 4) * 8 + e;  // 0..31
            float v;
            if (kt == 0)      v = U1[sub * G4H + col];
            else if (kt == 1) v = U1[(sub + 32) * G4H + col];
            else              v = (sub < 16) ? W1[sub * G4H + col]
                                             : ((sub == 16) ? b1[col] : 0.0f);
            wu1_sw[(f * 64 + lane) * 8 + e] = f2bf_rne(v * sc);
        }
    } else if (b < 96) {
        const int f = b - 48, jt = f / 12, g = (f / 3) & 3, kt = f % 3;
        const int col = g * 64 + jt * 16 + (lane & 15);
        const float sc = (g == 2) ? 1.0f : LOG2E;  // relu gate stays raw
        for (int e = 0; e < 8; ++e) {
            const int sub = (lane >> 4) * 8 + e;
            float v;
            if (kt == 0)      v = (sub < D_MLP) ? W2[sub * G4H + col]
                                                : ((sub == D_MLP) ? b2[col] : 0.0f);
            else if (kt == 1) v = U2[sub * G4H + col];
            else              v = U2[(sub + 32) * G4H + col];
            wu2_sw[(f * 64 + lane) * 8 + e] = f2bf_rne(v * sc);
        }
    } else if (b < 100) {
        const int fd = b - 96, nt = fd >> 1, kt = fd & 1;
        const int col = nt * 16 + (lane & 15);
        for (int e = 0; e < 8; ++e) {
            const int k = kt * 32 + (lane >> 4) * 8 + e;  // h1 dim 0..63
            const float v = (col < D_MLP) ? Wd[k * D_MLP + col] : 0.0f;
            wd_sw[(fd * 64 + lane) * 8 + e] = f2bf_rne(v);
        }
    } else {
        // bdp: real dense bias for cols 0..29; col 30 = 1.0 (bias activator for phase 2); col 31 = 0
        if (lane < 32)
            bdp[lane] = (lane < D_MLP) ? bd[lane] : ((lane == D_MLP) ? 1.0f : 0.0f);
    }
}

// ---------------- fully fused: LSTM1 -> Dense(D in LDS) -> LSTM2 -> projection ----------------
// Register strategy (r5): finish the 64-VGPR diet. r4 (px lane-pack -8, wd stream -8) hit the
// 64 budget but SPILLED ~1-2 dwords/thread/t (WRITE_SIZE 54MB) -> natural live was ~66-68.
// r5 adds bias-folding: bzv eliminated in BOTH phases (-8) by moving b1 into W1 row k=16
// (ax carries a 1.0 at q=2,e=0) and b2 into W2 row k=30 (D col 30 carries 1.0).
// Natural live ~58-62 -> 64 allocates clean. waves_per_eu(4,8): budget follows MAX (r1).
// TRIPWIRE: VGPR=64 + WRITE_SIZE >> 1MB => still spilling => revert attr to (3,4), keep diet.
__global__ __launch_bounds__(256)
__attribute__((amdgpu_waves_per_eu(4, 8)))
void lstm_all(const float* __restrict__ x, const short* __restrict__ wu1_sw,
              const short* __restrict__ wu2_sw, const short* __restrict__ wd_sw,
              const float* __restrict__ bdp, const float* __restrict__ Wf,
              const float* __restrict__ bfin, float* __restrict__ out) {
    __shared__ __align__(16) short P[2][BTILE * PSTR];        // 9216 B h-plane (dbuf)
    __shared__ __align__(16) short D[T_STEPS][BTILE * DSTR];  // 20480 B dense buffer
    // total 29696 B -> 5 blocks/CU (at VGPR <= 64)

    const int tid = threadIdx.x, lane = tid & 63, wave = tid >> 6;
    const int q = lane >> 4, n = lane & 15;
    const int b0 = blockIdx.x * BTILE;

    // ---- phase-1 weights: wave owns gate-col slice [g*64 + wave*16, +16) ----
    short8 wz[4][3];
#pragma unroll
    for (int g = 0; g < 4; ++g)
#pragma unroll
        for (int kt = 0; kt < 3; ++kt)
            wz[g][kt] = ((const short8*)wu1_sw)[(wave * 12 + g * 3 + kt) * 64 + lane];

    // d-projection: wave -> (row-tile mw, col-tile ntw); wd frags re-loaded per-t (L2-hot)
    const int mw = wave >> 1, ntw = wave & 1;
    const float bdv = bdp[ntw * 16 + n];

    // bias activator for the ax frag: lanes 32..47 (q==2) elem0 = bf16(1.0), else 0
    const unsigned bias0 = (lane >= 32 && lane < 48) ? 0x00003F80u : 0u;
    const bool hb = (lane >= 32);

    for (int i = tid; i < BTILE * PSTR; i += 256) P[0][i] = 0;

    float4_t cc[2];
    cc[0] = (float4_t){0, 0, 0, 0};
    cc[1] = (float4_t){0, 0, 0, 0};

    // x loads, lane-packed: EVERY lane loads its own 8 f32.
    // lane<32 -> m=0 rows (b0+n), lane>=32 -> m=1 rows (b0+16+n); k-half = (lane>>4)&1.
    const float* xlane = x + (size_t)(b0 + (lane >> 5) * 16 + n) * (T_STEPS * D_IN)
                           + ((lane >> 4) & 1) * 8;
    float4 px0 = *(const float4*)xlane;
    float4 px1 = *(const float4*)(xlane + 4);
    __syncthreads();  // P[0] zeros visible

    // ================= phase 1: LSTM1 (tanh) + Dense into D =================
    for (int t = 0; t < T_STEPS; ++t) {
        const short* cb = P[t & 1];
        short* nb = P[(t & 1) ^ 1];

        // wd frags: opaque pointer defeats LICM -> re-loaded each t, live range ends at d-proj.
        const short8* wp = (const short8*)wd_sw + (ntw * 2) * 64 + lane;
        asm volatile("" : "+v"(wp));
        const short8 wda = wp[0];
        const short8 wdb = wp[64];

        // build A-frags for x from lane-packed px; lanes>=32 are masked to the bias pattern
        // ({1.0 at k=16 for q==2, zeros elsewhere}) so W1 row16=b1 is activated exactly once.
        uint4 axu;
        axu.x = pk2bf(px0.x, px0.y);
        axu.y = pk2bf(px0.z, px0.w);
        axu.z = pk2bf(px1.x, px1.y);
        axu.w = pk2bf(px1.z, px1.w);
        uint4 axv;
        axv.x = __shfl_xor((int)axu.x, 32);
        axv.y = __shfl_xor((int)axu.y, 32);
        axv.z = __shfl_xor((int)axu.z, 32);
        axv.w = __shfl_xor((int)axu.w, 32);
        const uint4 bmask = (uint4){bias0, 0u, 0u, 0u};
        short8 axm[2];
        axm[0] = __builtin_bit_cast(short8, hb ? bmask : axu);
        axm[1] = __builtin_bit_cast(short8, hb ? bmask : axv);

        const int tn = (t + 1 < T_STEPS) ? t + 1 : T_STEPS - 1;
        px0 = *(const float4*)(xlane + tn * D_IN);
        px1 = *(const float4*)(xlane + tn * D_IN + 4);

#pragma unroll
        for (int m = 0; m < 2; ++m) {
            const int arow = (16 * m + n) * PSTR + q * 8;
            const short8 ah0 = *(const short8*)&cb[arow];
            const short8 ah1 = *(const short8*)&cb[arow + 32];
            float4_t ac[4];
#pragma unroll
            for (int g = 0; g < 4; ++g) {
                float4_t c = (float4_t){0, 0, 0, 0};
                c = mfma16(ah0, wz[g][0], c);
                c = mfma16(ah1, wz[g][1], c);
                c = mfma16(axm[m], wz[g][2], c);   // includes +b1 via k=16
                ac[g] = c;
            }
            // merged-rcp activation: 5 exp2 + 2 rcp per cell.
            // cn = c/(1+F) + (Q-1)/((1+B)(Q+1)) = [c*u + (Q-1)*v] * rcp(u*v),
            //   u=(1+B)(Q+1), v=(1+F);  h = (P-1) * rcp((1+A)(P+1)), P=2^(2*log2e*cn).
#pragma unroll
            for (int jj = 0; jj < 4; ++jj) {
                const float Bv = __builtin_amdgcn_exp2f(-ac[0][jj]);  // 2^-zi'
                const float Fv = __builtin_amdgcn_exp2f(-ac[1][jj]);  // 2^-zf'
                const float Qv = __builtin_amdgcn_exp2f(ac[2][jj]);   // 2^{zg''}
                const float Av = __builtin_amdgcn_exp2f(-ac[3][jj]);  // 2^-zo'
                const float uu = (1.0f + Bv) * (Qv + 1.0f);
                const float vv = 1.0f + Fv;
                const float num = cc[m][jj] * uu + (Qv - 1.0f) * vv;
                const float cn = num * __builtin_amdgcn_rcpf(uu * vv);
                cc[m][jj] = cn;
                const float Pv = __builtin_amdgcn_exp2f(cn * TWO_LOG2E);
                const float ww = (1.0f + Av) * (Pv + 1.0f);
                const float hh = (Pv - 1.0f) * __builtin_amdgcn_rcpf(ww);
                nb[(16 * m + q * 4 + jj) * PSTR + wave * 16 + n] = f2bf(hh);
            }
        }
        __syncthreads();  // h1_t complete (also drains wd/px loads)

        // d_t = h1_t @ Wd + bd -> D[t]  (each wave: one 16x16 tile, k=64)
        // col 30 gets 0 + bdv(=1.0) -> exact 1.0 in bf16: the phase-2 bias activator.
        {
            const int drow = (16 * mw + n) * PSTR + q * 8;
            const short8 dh0 = *(const short8*)&nb[drow];
            const short8 dh1 = *(const short8*)&nb[drow + 32];
            float4_t dd = (float4_t){bdv, bdv, bdv, bdv};
            dd = mfma16(dh0, wda, dd);
            dd = mfma16(dh1, wdb, dd);
            short* dt = &D[t][0];
#pragma unroll
            for (int jj = 0; jj < 4; ++jj)
                dt[(16 * mw + q * 4 + jj) * DSTR + ntw * 16 + n] = f2bf(dd[jj]);
        }
    }

    // ================= phase boundary =================
    __syncthreads();  // all d-reads of P done before re-zeroing
#pragma unroll
    for (int g = 0; g < 4; ++g)
#pragma unroll
        for (int kt = 0; kt < 3; ++kt)
            wz[g][kt] = ((const short8*)wu2_sw)[(wave * 12 + g * 3 + kt) * 64 + lane];
    cc[0] = (float4_t){0, 0, 0, 0};
    cc[1] = (float4_t){0, 0, 0, 0};
    for (int i = tid; i < BTILE * PSTR; i += 256) P[0][i] = 0;
    __syncthreads();

    // ================= phase 2: LSTM2 (relu) from D =================
    for (int t = 0; t < T_STEPS; ++t) {
        const short* cb = P[t & 1];
        short* nb = P[(t & 1) ^ 1];

#pragma unroll
        for (int m = 0; m < 2; ++m) {
            const int ar = 16 * m + n;
            const short8 ad  = *(const short8*)&D[t][ar * DSTR + q * 8];
            const short8 ah0 = *(const short8*)&cb[ar * PSTR + q * 8];
            const short8 ah1 = *(const short8*)&cb[ar * PSTR + 32 + q * 8];
            float4_t ac[4];
#pragma unroll
            for (int g = 0; g < 4; ++g) {
                float4_t c = (float4_t){0, 0, 0, 0};
                c = mfma16(ad, wz[g][0], c);       // includes +b2 via d[...,30]==1.0 x W2 row30
                c = mfma16(ah0, wz[g][1], c);
                c = mfma16(ah1, wz[g][2], c);
                ac[g] = c;
            }
#pragma unroll
            for (int jj = 0; jj < 4; ++jj) {
                const float iv = sigm2(ac[0][jj]);
                const float fv = sigm2(ac[1][jj]);
                const float gv = fmaxf(ac[2][jj], 0.0f);   // raw (unscaled) gate
                const float ov = sigm2(ac[3][jj]);
                const float cn = fv * cc[m][jj] + iv * gv;
                cc[m][jj] = cn;
                nb[(16 * m + q * 4 + jj) * PSTR + wave * 16 + n] = f2bf(ov * fmaxf(cn, 0.0f));
            }
        }
        __syncthreads();
    }

    // ---- out = h2_9 @ Wf + bf ; t=9 wrote nb = P[0] ----
    if (tid < 128) {
        const int r = tid >> 2, c = tid & 3;
        float s = bfin[c];
#pragma unroll
        for (int kb = 0; kb < 8; ++kb) {
            const short8 h8 = *(const short8*)&P[0][r * PSTR + kb * 8];
#pragma unroll
            for (int e = 0; e < 8; ++e)
                s += bf2f(h8[e]) * Wf[(kb * 8 + e) * D_OUT + c];
        }
        out[(size_t)(b0 + r) * D_OUT + c] = s;
    }
}

extern "C" void kernel_launch(void* const* d_in, const int* in_sizes, int n_in,
                              void* d_out, int out_size, void* d_ws, size_t ws_size,
                              hipStream_t stream) {
    const float* x  = (const float*)d_in[0];
    const float* W1 = (const float*)d_in[1];
    const float* U1 = (const float*)d_in[2];
    const float* b1 = (const float*)d_in[3];
    const float* Wd = (const float*)d_in[4];
    const float* bd = (const float*)d_in[5];
    const float* W2 = (const float*)d_in[6];
    const float* U2 = (const float*)d_in[7];
    const float* b2 = (const float*)d_in[8];
    const float* Wf = (const float*)d_in[9];
    const float* bf = (const float*)d_in[10];
    float* out = (float*)d_out;

    char* ws = (char*)d_ws;
    short* wu1_sw = (short*)(ws + WS_WU1);
    short* wu2_sw = (short*)(ws + WS_WU2);
    short* wd_sw  = (short*)(ws + WS_WD);
    float* bdp    = (float*)(ws + WS_BDP);

    precompute<<<101, 64, 0, stream>>>(W1, U1, b1, Wd, bd, W2, U2, b2,
                                       wu1_sw, wu2_sw, wd_sw, bdp);
    lstm_all<<<B_TOT / BTILE, 256, 0, stream>>>(x, wu1_sw, wu2_sw, wd_sw,
                                                bdp, Wf, bf, out);
}

// Round 7
// 183.579 us; speedup vs baseline: 1.0959x; 1.0189x over previous
//
#include <hip/hip_runtime.h>

#define B_TOT 65536
#define T_STEPS 10
#define D_IN 16
#define H 64
#define G4H 256
#define D_MLP 30
#define D_OUT 4
#define BTILE 32
#define PSTR 72     // h-plane row stride (shorts): 144B rows -> ds_read_b128 ALIGNED; 36dw -> 2-way only
#define DSTR 32     // d buffer row stride (shorts): 64B rows -> aligned + contiguous ad reads
#define LOG2E 1.44269504088896340736f
#define TWO_LOG2E 2.88539008177792681472f

typedef short short8 __attribute__((ext_vector_type(8)));
typedef float float4_t __attribute__((ext_vector_type(4)));
typedef __bf16 bf16x8_t __attribute__((ext_vector_type(8)));

static __device__ __forceinline__ short f2bf(float f) {  // round-half-up (activations)
    unsigned u = __builtin_bit_cast(unsigned, f);
    return (short)(unsigned short)((u + 0x8000u) >> 16);
}
static __device__ __forceinline__ short f2bf_rne(float f) {  // weights
    unsigned u = __builtin_bit_cast(unsigned, f);
    unsigned r = (u + 0x7FFFu + ((u >> 16) & 1u)) >> 16;
    return (short)(unsigned short)r;
}
static __device__ __forceinline__ float bf2f(short s) {
    unsigned u = ((unsigned)(unsigned short)s) << 16;
    return __builtin_bit_cast(float, u);
}
static __device__ __forceinline__ float4_t mfma16(short8 a, short8 b, float4_t c) {
    return __builtin_amdgcn_mfma_f32_16x16x32_bf16(
        __builtin_bit_cast(bf16x8_t, a), __builtin_bit_cast(bf16x8_t, b), c, 0, 0, 0);
}
// pack two f32 -> one dword of 2 bf16 (round-half-up, same bits as f2bf pairwise)
static __device__ __forceinline__ unsigned pk2bf(float lo, float hi) {
    const unsigned ulo = __builtin_bit_cast(unsigned, lo) + 0x8000u;
    const unsigned uhi = __builtin_bit_cast(unsigned, hi) + 0x8000u;
    return (ulo >> 16) | (uhi & 0xFFFF0000u);
}

// ---- workspace layout (bytes) ----
#define WS_WU1 0        // 48 frags x 1KB = 49152
#define WS_WU2 49152    // 48 frags = 49152
#define WS_WD  98304    // 4 frags = 4096
#define WS_BDP 102400   // 32 f32

// Weights pre-swizzled to MFMA B-frag order (frag f, lane l, elem e -> B[k=(l>>4)*8+e][n=l&15])
// and pre-scaled: i/f/o gates by log2e, L1 g-gate by 2*log2e, L2 g-gate (relu) raw.
// TRANSPOSE DUALITY (r7): the same register bits serve as an A-frag of U^T
// (A'[r=l&15][k=(l>>4)*8+e] = U[k][r]), so z^T = mfma(wz, h_frag) needs NO new layouts.
// BIAS FOLDING (r5): b1 in wu1 kt2 row k=16 (activated by 1.0 in ax); b2 in wu2 kt0 row
// k=30 (activated by d[...,30]==1.0 via bdp[30]=1.0).
// wu1: A1=[h1(0:64)|x(16)|1|0...], kt0=U1[0:32], kt1=U1[32:64], kt2=[W1(16);b1;zeros(15)]
// wu2: A2=[d(0:30)|1|0|h2(0:64)], kt0=[W2(30);b2;0], kt1=U2[0:32], kt2=U2[32:64]
// wd : d = h1 @ Wd (cols padded 30->32, col30 forced to 1.0 via bdp), unscaled
__global__ void precompute(const float* __restrict__ W1, const float* __restrict__ U1,
                           const float* __restrict__ b1, const float* __restrict__ Wd,
                           const float* __restrict__ bd, const float* __restrict__ W2,
                           const float* __restrict__ U2, const float* __restrict__ b2,
                           short* __restrict__ wu1_sw, short* __restrict__ wu2_sw,
                           short* __restrict__ wd_sw, float* __restrict__ bdp) {
    const int lane = threadIdx.x;  // 64
    const int b = blockIdx.x;      // 101
    if (b < 48) {
        const int f = b, jt = f / 12, g = (f / 3) & 3, kt = f % 3;
        const int col = g * 64 + jt * 16 + (lane & 15);
        const float sc = (g == 2) ? TWO_LOG2E : LOG2E;
        for (int e = 0; e < 8; ++e) {
            const int sub = (lane >> 4) * 8 + e;  // 0..31
            float v;
            if (kt == 0)      v = U1[sub * G4H + col];
            else if (kt == 1) v = U1[(sub + 32) * G4H + col];
            else              v = (sub < 16) ? W1[sub * G4H + col]
                                             : ((sub == 16) ? b1[col] : 0.0f);
            wu1_sw[(f * 64 + lane) * 8 + e] = f2bf_rne(v * sc);
        }
    } else if (b < 96) {
        const int f = b - 48, jt = f / 12, g = (f / 3) & 3, kt = f % 3;
        const int col = g * 64 + jt * 16 + (lane & 15);
        const float sc = (g == 2) ? 1.0f : LOG2E;  // relu gate stays raw
        for (int e = 0; e < 8; ++e) {
            const int sub = (lane >> 4) * 8 + e;
            float v;
            if (kt == 0)      v = (sub < D_MLP) ? W2[sub * G4H + col]
                                                : ((sub == D_MLP) ? b2[col] : 0.0f);
            else if (kt == 1) v = U2[sub * G4H + col];
            else              v = U2[(sub + 32) * G4H + col];
            wu2_sw[(f * 64 + lane) * 8 + e] = f2bf_rne(v * sc);
        }
    } else if (b < 100) {
        const int fd = b - 96, nt = fd >> 1, kt = fd & 1;
        const int col = nt * 16 + (lane & 15);
        for (int e = 0; e < 8; ++e) {
            const int k = kt * 32 + (lane >> 4) * 8 + e;  // h1 dim 0..63
            const float v = (col < D_MLP) ? Wd[k * D_MLP + col] : 0.0f;
            wd_sw[(fd * 64 + lane) * 8 + e] = f2bf_rne(v);
        }
    } else {
        // bdp: dense bias cols 0..29; col 30 = 1.0 (phase-2 bias activator); col 31 = 0
        if (lane < 32)
            bdp[lane] = (lane < D_MLP) ? bd[lane] : ((lane == D_MLP) ? 1.0f : 0.0f);
    }
}

// ---------------- fully fused: LSTM1 -> Dense(D in LDS) -> LSTM2 -> projection ----------------
// r7: operand-swapped (transposed) gate MFMAs. Output C-layout now gives each thread 4
// CONSECUTIVE h-columns of ONE row (cell: batch=16m+n, hcol=wave*16+q*4+jj) -> h written as
// ONE ds_write_b64 (2x pk2bf) instead of 4 scattered b16 writes + 8 f2bf. 144B rows -> the
// b64 writes alias only 2-way (free, m136). d-proj and out-proj unchanged.
// Phase-2 activation rcp-merged 3->2: cn=[c(1+B)+g'(1+F)]*rcp(den), h=max(num,0)*rcp(den(1+A)).
// Register state (r6 measured): VGPR=64, 5 blocks/CU, residual one-shot spill ~16B/thread.
__global__ __launch_bounds__(256)
__attribute__((amdgpu_waves_per_eu(4, 8)))
void lstm_all(const float* __restrict__ x, const short* __restrict__ wu1_sw,
              const short* __restrict__ wu2_sw, const short* __restrict__ wd_sw,
              const float* __restrict__ bdp, const float* __restrict__ Wf,
              const float* __restrict__ bfin, float* __restrict__ out) {
    __shared__ __align__(16) short P[2][BTILE * PSTR];        // 9216 B h-plane (dbuf)
    __shared__ __align__(16) short D[T_STEPS][BTILE * DSTR];  // 20480 B dense buffer
    // total 29696 B -> 5 blocks/CU (at VGPR <= 64)

    const int tid = threadIdx.x, lane = tid & 63, wave = tid >> 6;
    const int q = lane >> 4, n = lane & 15;
    const int b0 = blockIdx.x * BTILE;

    // ---- phase-1 weights: wave owns gate-col slice [g*64 + wave*16, +16) ----
    short8 wz[4][3];
#pragma unroll
    for (int g = 0; g < 4; ++g)
#pragma unroll
        for (int kt = 0; kt < 3; ++kt)
            wz[g][kt] = ((const short8*)wu1_sw)[(wave * 12 + g * 3 + kt) * 64 + lane];

    // d-projection: wave -> (row-tile mw, col-tile ntw); wd frags re-loaded per-t (L2-hot)
    const int mw = wave >> 1, ntw = wave & 1;
    const float bdv = bdp[ntw * 16 + n];

    // bias activator for the ax frag: lanes 32..47 (q==2) elem0 = bf16(1.0), else 0
    const unsigned bias0 = (lane >= 32 && lane < 48) ? 0x00003F80u : 0u;
    const bool hb = (lane >= 32);

    for (int i = tid; i < BTILE * PSTR; i += 256) P[0][i] = 0;

    float4_t cc[2];
    cc[0] = (float4_t){0, 0, 0, 0};
    cc[1] = (float4_t){0, 0, 0, 0};

    // x loads, lane-packed: EVERY lane loads its own 8 f32.
    // lane<32 -> m=0 rows (b0+n), lane>=32 -> m=1 rows (b0+16+n); k-half = (lane>>4)&1.
    const float* xlane = x + (size_t)(b0 + (lane >> 5) * 16 + n) * (T_STEPS * D_IN)
                           + ((lane >> 4) & 1) * 8;
    float4 px0 = *(const float4*)xlane;
    float4 px1 = *(const float4*)(xlane + 4);
    __syncthreads();  // P[0] zeros visible

    // ================= phase 1: LSTM1 (tanh) + Dense into D =================
    for (int t = 0; t < T_STEPS; ++t) {
        const short* cb = P[t & 1];
        short* nb = P[(t & 1) ^ 1];

        // wd frags: opaque pointer defeats LICM -> re-loaded each t, live range ends at d-proj.
        const short8* wp = (const short8*)wd_sw + (ntw * 2) * 64 + lane;
        asm volatile("" : "+v"(wp));
        const short8 wda = wp[0];
        const short8 wdb = wp[64];

        // x frags (serve as B-operand = x^T in the swapped MFMA; same bits either way).
        // lanes>=32 masked to the bias pattern (1.0 at k=16 for q==2) -> W1 row16=b1 fires once.
        uint4 axu;
        axu.x = pk2bf(px0.x, px0.y);
        axu.y = pk2bf(px0.z, px0.w);
        axu.z = pk2bf(px1.x, px1.y);
        axu.w = pk2bf(px1.z, px1.w);
        uint4 axv;
        axv.x = __shfl_xor((int)axu.x, 32);
        axv.y = __shfl_xor((int)axu.y, 32);
        axv.z = __shfl_xor((int)axu.z, 32);
        axv.w = __shfl_xor((int)axu.w, 32);
        const uint4 bmask = (uint4){bias0, 0u, 0u, 0u};
        short8 axm[2];
        axm[0] = __builtin_bit_cast(short8, hb ? bmask : axu);
        axm[1] = __builtin_bit_cast(short8, hb ? bmask : axv);

        const int tn = (t + 1 < T_STEPS) ? t + 1 : T_STEPS - 1;
        px0 = *(const float4*)(xlane + tn * D_IN);
        px1 = *(const float4*)(xlane + tn * D_IN + 4);

#pragma unroll
        for (int m = 0; m < 2; ++m) {
            const int arow = (16 * m + n) * PSTR + q * 8;
            const short8 ah0 = *(const short8*)&cb[arow];
            const short8 ah1 = *(const short8*)&cb[arow + 32];
            float4_t ac[4];
#pragma unroll
            for (int g = 0; g < 4; ++g) {
                // SWAPPED operands: computes z^T; ac[g][jj] = gate g for cell
                // (batch=16m+n, hcol=wave*16+q*4+jj). Same frag registers as before.
                float4_t c = (float4_t){0, 0, 0, 0};
                c = mfma16(wz[g][0], ah0, c);
                c = mfma16(wz[g][1], ah1, c);
                c = mfma16(wz[g][2], axm[m], c);   // includes +b1 via k=16
                ac[g] = c;
            }
            // merged-rcp activation: 5 exp2 + 2 rcp per cell.
            float hv[4];
#pragma unroll
            for (int jj = 0; jj < 4; ++jj) {
                const float Bv = __builtin_amdgcn_exp2f(-ac[0][jj]);  // 2^-zi'
                const float Fv = __builtin_amdgcn_exp2f(-ac[1][jj]);  // 2^-zf'
                const float Qv = __builtin_amdgcn_exp2f(ac[2][jj]);   // 2^{zg''}
                const float Av = __builtin_amdgcn_exp2f(-ac[3][jj]);  // 2^-zo'
                const float uu = (1.0f + Bv) * (Qv + 1.0f);
                const float vv = 1.0f + Fv;
                const float num = cc[m][jj] * uu + (Qv - 1.0f) * vv;
                const float cn = num * __builtin_amdgcn_rcpf(uu * vv);
                cc[m][jj] = cn;
                const float Pv = __builtin_amdgcn_exp2f(cn * TWO_LOG2E);
                const float ww = (1.0f + Av) * (Pv + 1.0f);
                hv[jj] = (Pv - 1.0f) * __builtin_amdgcn_rcpf(ww);
            }
            // one packed 8B write: row 16m+n, cols wave*16+q*4..+3 (8B-aligned; 2-way bank)
            *(uint2*)&nb[(16 * m + n) * PSTR + wave * 16 + q * 4] =
                (uint2){pk2bf(hv[0], hv[1]), pk2bf(hv[2], hv[3])};
        }
        __syncthreads();  // h1_t complete (also drains wd/px loads)

        // d_t = h1_t @ Wd + bd -> D[t]  (each wave: one 16x16 tile, k=64) — UNTRANSPOSED
        // col 30 gets 0 + bdv(=1.0) -> exact 1.0 in bf16: the phase-2 bias activator.
        {
            const int drow = (16 * mw + n) * PSTR + q * 8;
            const short8 dh0 = *(const short8*)&nb[drow];
            const short8 dh1 = *(const short8*)&nb[drow + 32];
            float4_t dd = (float4_t){bdv, bdv, bdv, bdv};
            dd = mfma16(dh0, wda, dd);
            dd = mfma16(dh1, wdb, dd);
            short* dt = &D[t][0];
#pragma unroll
            for (int jj = 0; jj < 4; ++jj)
                dt[(16 * mw + q * 4 + jj) * DSTR + ntw * 16 + n] = f2bf(dd[jj]);
        }
    }

    // ================= phase boundary =================
    __syncthreads();  // all d-reads of P done before re-zeroing
#pragma unroll
    for (int g = 0; g < 4; ++g)
#pragma unroll
        for (int kt = 0; kt < 3; ++kt)
            wz[g][kt] = ((const short8*)wu2_sw)[(wave * 12 + g * 3 + kt) * 64 + lane];
    cc[0] = (float4_t){0, 0, 0, 0};
    cc[1] = (float4_t){0, 0, 0, 0};
    for (int i = tid; i < BTILE * PSTR; i += 256) P[0][i] = 0;
    __syncthreads();

    // ================= phase 2: LSTM2 (relu) from D =================
    for (int t = 0; t < T_STEPS; ++t) {
        const short* cb = P[t & 1];
        short* nb = P[(t & 1) ^ 1];

#pragma unroll
        for (int m = 0; m < 2; ++m) {
            const int ar = 16 * m + n;
            const short8 ad  = *(const short8*)&D[t][ar * DSTR + q * 8];
            const short8 ah0 = *(const short8*)&cb[ar * PSTR + q * 8];
            const short8 ah1 = *(const short8*)&cb[ar * PSTR + 32 + q * 8];
            float4_t ac[4];
#pragma unroll
            for (int g = 0; g < 4; ++g) {
                // SWAPPED operands: ac[g][jj] = gate g for cell (batch=16m+n, hcol=wave*16+q*4+jj)
                float4_t c = (float4_t){0, 0, 0, 0};
                c = mfma16(wz[g][0], ad, c);       // includes +b2 via d[...,30]==1.0 x W2 row30
                c = mfma16(wz[g][1], ah0, c);
                c = mfma16(wz[g][2], ah1, c);
                ac[g] = c;
            }
            // merged-rcp relu activation: 3 exp2 + 2 rcp per cell (was 3+3).
            // cn = [c(1+B) + g'(1+F)] * rcp((1+B)(1+F));  h = max(num,0) * rcp(den*(1+A)).
            float hv[4];
#pragma unroll
            for (int jj = 0; jj < 4; ++jj) {
                const float Bv = __builtin_amdgcn_exp2f(-ac[0][jj]);
                const float Fv = __builtin_amdgcn_exp2f(-ac[1][jj]);
                const float gp = fmaxf(ac[2][jj], 0.0f);   // raw (unscaled) gate
                const float Av = __builtin_amdgcn_exp2f(-ac[3][jj]);
                const float eb = 1.0f + Bv, ef = 1.0f + Fv;
                const float num = cc[m][jj] * eb + gp * ef;
                const float den = eb * ef;                  // > 0 always
                const float cn = num * __builtin_amdgcn_rcpf(den);
                cc[m][jj] = cn;
                hv[jj] = fmaxf(num, 0.0f) * __builtin_amdgcn_rcpf(den * (1.0f + Av));
            }
            *(uint2*)&nb[ar * PSTR + wave * 16 + q * 4] =
                (uint2){pk2bf(hv[0], hv[1]), pk2bf(hv[2], hv[3])};
        }
        __syncthreads();
    }

    // ---- out = h2_9 @ Wf + bf ; t=9 wrote nb = P[0] ----
    if (tid < 128) {
        const int r = tid >> 2, c = tid & 3;
        float s = bfin[c];
#pragma unroll
        for (int kb = 0; kb < 8; ++kb) {
            const short8 h8 = *(const short8*)&P[0][r * PSTR + kb * 8];
#pragma unroll
            for (int e = 0; e < 8; ++e)
                s += bf2f(h8[e]) * Wf[(kb * 8 + e) * D_OUT + c];
        }
        out[(size_t)(b0 + r) * D_OUT + c] = s;
    }
}

extern "C" void kernel_launch(void* const* d_in, const int* in_sizes, int n_in,
                              void* d_out, int out_size, void* d_ws, size_t ws_size,
                              hipStream_t stream) {
    const float* x  = (const float*)d_in[0];
    const float* W1 = (const float*)d_in[1];
    const float* U1 = (const float*)d_in[2];
    const float* b1 = (const float*)d_in[3];
    const float* Wd = (const float*)d_in[4];
    const float* bd = (const float*)d_in[5];
    const float* W2 = (const float*)d_in[6];
    const float* U2 = (const float*)d_in[7];
    const float* b2 = (const float*)d_in[8];
    const float* Wf = (const float*)d_in[9];
    const float* bf = (const float*)d_in[10];
    float* out = (float*)d_out;

    char* ws = (char*)d_ws;
    short* wu1_sw = (short*)(ws + WS_WU1);
    short* wu2_sw = (short*)(ws + WS_WU2);
    short* wd_sw  = (short*)(ws + WS_WD);
    float* bdp    = (float*)(ws + WS_BDP);

    precompute<<<101, 64, 0, stream>>>(W1, U1, b1, Wd, bd, W2, U2, b2,
                                       wu1_sw, wu2_sw, wd_sw, bdp);
    lstm_all<<<B_TOT / BTILE, 256, 0, stream>>>(x, wu1_sw, wu2_sw, wd_sw,
                                                bdp, Wf, bf, out);
}